// Round 2
// baseline (175.763 us; speedup 1.0000x reference)
//
#include <hip/hip_runtime.h>

// 3D db4 DWT, fused single kernel.
// x: [4,3,32,256,256] f32 -> out: [4,24,16,128,128] f32
// out[b, (4*st+2*sh+sw)*3+c, to, ho, wo]

#define BB 4
#define CC 3
#define TT 32
#define HH 256
#define WW 256
#define TOH 16
#define HOH 128
#define WOH 128

#define TH 4            // output rows (h) per tile
#define TW 32           // output cols (w) per tile
#define IH (2*TH+6)     // 14 input rows per slice
#define IW (2*TW+6)     // 70 input cols per slice
#define ASTR 71         // LDS row stride for input tile (odd -> bank-friendly)
#define MW (2*TW)       // 64
#define MSTR 66         // LDS row stride for W-transformed tile

#define NTHREADS 512

// Pre-flipped db4 filters: g[j] = filt[7-j], so y[n] = sum_j xa[2n+j-3]*g[j]
constexpr float GLO[8] = {
     0.23037781330885523f,  0.7148465705525415f,   0.6308807679295904f,
    -0.02798376941698385f, -0.18703481171888114f,  0.030841381835986965f,
     0.032883011666982945f, -0.010597401784997278f };
constexpr float GHI[8] = {
    -0.010597401784997278f, -0.032883011666982945f, 0.030841381835986965f,
     0.18703481171888114f,  -0.02798376941698385f,  -0.6308807679295904f,
     0.7148465705525415f,   -0.23037781330885523f };

__device__ __forceinline__ int refl(int p, int n) {
    p = p < 0 ? -p : p;
    p = p >= n ? 2 * n - 2 - p : p;
    return p;
}

__global__ __launch_bounds__(NTHREADS)
void dwt3d_db4_kernel(const float* __restrict__ x, float* __restrict__ out) {
    __shared__ float Abuf[IH * ASTR];   // staged input slice region
    __shared__ float Mbuf[IH * MSTR];   // after W transform: rows x (lo[32] | hi[32])

    const int tid = threadIdx.x;
    const int bz = blockIdx.z;              // b*CC + c
    const int b = bz / CC, c = bz - b * CC;
    const int ho0 = blockIdx.y * TH;        // output-h tile origin
    const int wo0 = blockIdx.x * TW;        // output-w tile origin

    const float* xs = x + (size_t)bz * (TT * HH * WW);

    // ---- per-thread column identity (for H phase + output) ----
    const int wo    = tid & 31;         // 0..31
    const int hoq   = (tid >> 5) & 3;   // 0..3
    const int subhw = tid >> 7;         // 0..3 = 2*sh+sw
    const int sh    = subhw >> 1;
    const int sw    = subhw & 1;

    // H-phase weights (fixed per thread)
    float wH[8];
#pragma unroll
    for (int j = 0; j < 8; ++j) wH[j] = sh ? GHI[j] : GLO[j];
    const int hm_base = sw * TW + wo;

    // ---- precompute load slots (indices are t-invariant) ----
    int a_off0, g_off0, a_off1 = 0, g_off1 = 0;
    {
        int i = tid;
        int r = i / IW, cl = i - r * IW;
        a_off0 = r * ASTR + cl;
        g_off0 = refl(2 * ho0 - 3 + r, HH) * WW + refl(2 * wo0 - 3 + cl, WW);
    }
    const bool act1 = (tid + NTHREADS) < IH * IW;   // 980 total elements
    if (act1) {
        int i = tid + NTHREADS;
        int r = i / IW, cl = i - r * IW;
        a_off1 = r * ASTR + cl;
        g_off1 = refl(2 * ho0 - 3 + r, HH) * WW + refl(2 * wo0 - 3 + cl, WW);
    }

    // ---- W-phase identity ----
    const bool wact = tid < IH * TW;    // 448 workers
    const int wr = tid >> 5;            // row 0..13
    const int ww2 = tid & 31;           // output w 0..31
    const int wa_base = wr * ASTR + 2 * ww2;
    const int wm_base = wr * MSTR + ww2;

    float v[TT];    // per-thread column of HW-transformed values, one per t

#pragma unroll
    for (int t = 0; t < TT; ++t) {
        const float* xt = xs + (size_t)t * (HH * WW);
        // stage input region for slice t
        Abuf[a_off0] = xt[g_off0];
        if (act1) Abuf[a_off1] = xt[g_off1];
        __syncthreads();

        // W transform: each worker computes lo+hi for one (row, wo)
        if (wact) {
            float alo = 0.f, ahi = 0.f;
#pragma unroll
            for (int j = 0; j < 8; ++j) {
                float a = Abuf[wa_base + j];
                alo = fmaf(a, GLO[j], alo);
                ahi = fmaf(a, GHI[j], ahi);
            }
            Mbuf[wm_base]      = alo;
            Mbuf[wm_base + TW] = ahi;
        }
        __syncthreads();

        // H transform: one value per thread-column
        float acc = 0.f;
#pragma unroll
        for (int j = 0; j < 8; ++j)
            acc = fmaf(Mbuf[(2 * hoq + j) * MSTR + hm_base], wH[j], acc);
        v[t] = acc;
        // next iteration's Abuf writes are safe after the barrier inside next iter
    }

    // ---- T transform (registers only) + store ----
    // out[b][(4*st+subhw)*3+c][to][ho0+hoq][wo0+wo]
    const size_t hw = (size_t)(ho0 + hoq) * WOH + (wo0 + wo);
    const size_t ch_lo = (size_t)(subhw * CC + c);
    const size_t ch_hi = (size_t)((4 + subhw) * CC + c);
    const size_t o_lo = (((size_t)b * 24 + ch_lo) * TOH) * (HOH * WOH) + hw;
    const size_t o_hi = (((size_t)b * 24 + ch_hi) * TOH) * (HOH * WOH) + hw;

#pragma unroll
    for (int to = 0; to < TOH; ++to) {
        float lo = 0.f, hi = 0.f;
#pragma unroll
        for (int j = 0; j < 8; ++j) {
            int p = 2 * to + j - 3;
            p = p < 0 ? -p : p;
            p = p >= TT ? 2 * TT - 2 - p : p;   // folds to constant
            lo = fmaf(v[p], GLO[j], lo);
            hi = fmaf(v[p], GHI[j], hi);
        }
        out[o_lo + (size_t)to * (HOH * WOH)] = lo;
        out[o_hi + (size_t)to * (HOH * WOH)] = hi;
    }
}

extern "C" void kernel_launch(void* const* d_in, const int* in_sizes, int n_in,
                              void* d_out, int out_size, void* d_ws, size_t ws_size,
                              hipStream_t stream) {
    (void)in_sizes; (void)n_in; (void)d_ws; (void)ws_size; (void)out_size;
    const float* x = (const float*)d_in[0];
    float* out = (float*)d_out;
    dim3 grid(WOH / TW, HOH / TH, BB * CC);   // (4, 32, 12) = 1536 blocks
    dim3 block(NTHREADS);
    hipLaunchKernelGGL(dwt3d_db4_kernel, grid, block, 0, stream, x, out);
}

// Round 5
// 75.375 us; speedup vs baseline: 2.3318x; 2.3318x over previous
//
#include <hip/hip_runtime.h>

// 3D db4 DWT, fused single kernel, wave-private slice pipeline (zero barriers
// in main loop, register-double-buffered staging, one barrier before T-phase).
// x: [4,3,32,256,256] f32 -> out: [4,24,16,128,128] f32
// out[b, (4*st+2*sh+sw)*3+c, to, ho, wo]

#define CC 3
#define TT 32
#define HH 256
#define WW 256
#define TOH 16
#define HOH 128
#define WOH 128

#define TH 4            // output rows (h) per tile
#define TW 32           // output cols (w) per tile
#define IH 14           // 2*TH+6 input rows per slice
#define IW 70           // 2*TW+6 input cols per slice
#define ASTR 72         // LDS row stride (floats), keeps float2 8B-aligned
#define AWAVE (IH*ASTR) // 1008 floats per wave region
#define NELEM (IH*IW)   // 980 staged elements per slice
#define NSLOT 16        // ceil(980/64)
#define NW 8
#define NTHREADS 512
#define VSTR 512        // Vbuf row stride (floats)

// Pre-flipped db4 filters: g[j] = filt[7-j], so y[n] = sum_j xa[2n+j-3]*g[j]
constexpr float GLO[8] = {
     0.23037781330885523f,  0.7148465705525415f,   0.6308807679295904f,
    -0.02798376941698385f, -0.18703481171888114f,  0.030841381835986965f,
     0.032883011666982945f, -0.010597401784997278f };
constexpr float GHI[8] = {
    -0.010597401784997278f, -0.032883011666982945f, 0.030841381835986965f,
     0.18703481171888114f,  -0.02798376941698385f,  -0.6308807679295904f,
     0.7148465705525415f,   -0.23037781330885523f };

__device__ __forceinline__ int refl(int p, int n) {
    p = p < 0 ? -p : p;
    p = p >= n ? 2 * n - 2 - p : p;
    return p;
}

__global__ __launch_bounds__(NTHREADS)
void dwt3d_db4_kernel(const float* __restrict__ x, float* __restrict__ out) {
    __shared__ float Abuf[NW * AWAVE];   // 32.25 KB: per-wave input regions
    __shared__ float Vbuf[TT * VSTR];    // 64 KB: HW-transformed, [t][col]

    const int tid  = threadIdx.x;
    const int wid  = tid >> 6;
    const int lane = tid & 63;
    const int wo   = lane & 31;          // lane's output-w column
    const int sw   = lane >> 5;          // lane's W-subband (0=lo, 1=hi)

    const int bz = blockIdx.z;           // b*CC + c
    const int b = bz / CC, c = bz - b * CC;
    const int ho0 = blockIdx.y * TH;
    const int wo0 = blockIdx.x * TW;
    const float* xs = x + (size_t)bz * (TT * HH * WW);

    // ---- staging offsets (t-invariant) ----
    int g_off[NSLOT], a_off[NSLOT];
#pragma unroll
    for (int k = 0; k < NSLOT; ++k) {
        int i = lane + 64 * k;
        int ii = i < NELEM ? i : 0;
        int r = ii / IW, cl = ii - r * IW;
        a_off[k] = wid * AWAVE + r * ASTR + cl;
        g_off[k] = refl(2 * ho0 - 3 + r, HH) * WW + refl(2 * wo0 - 3 + cl, WW);
    }

    // per-lane W weights (select by sw)
    float wG[8];
#pragma unroll
    for (int j = 0; j < 8; ++j) wG[j] = sw ? GHI[j] : GLO[j];

    const int abase = wid * AWAVE + 2 * wo;
    const int t0 = wid * 4;              // this wave's 4 slices

#define LOADS(P, t) do {                                                   \
        const float* xt = xs + (size_t)(t) * (HH * WW);                    \
        _Pragma("unroll")                                                  \
        for (int k = 0; k < NSLOT; ++k) P[k] = xt[g_off[k]];               \
    } while (0)

#define WRITEA(P) do {                                                     \
        _Pragma("unroll")                                                  \
        for (int k = 0; k < NSLOT; ++k)                                    \
            if (lane + 64 * k < NELEM) Abuf[a_off[k]] = P[k];              \
    } while (0)

    // W in LDS->reg, H entirely in registers (lane owns its (sw,wo) column)
#define COMPUTE(t) do {                                                    \
        float vacc[8] = {0.f,0.f,0.f,0.f,0.f,0.f,0.f,0.f};                 \
        _Pragma("unroll")                                                  \
        for (int r = 0; r < IH; ++r) {                                     \
            float m = 0.f;                                                 \
            _Pragma("unroll")                                              \
            for (int j = 0; j < 8; ++j)                                    \
                m = fmaf(Abuf[abase + r * ASTR + j], wG[j], m);            \
            _Pragma("unroll")                                              \
            for (int ho = 0; ho < 4; ++ho) {                               \
                const int j = r - 2 * ho;                                  \
                if (j >= 0 && j < 8) {                                     \
                    vacc[ho]     = fmaf(m, GLO[j], vacc[ho]);              \
                    vacc[4 + ho] = fmaf(m, GHI[j], vacc[4 + ho]);          \
                }                                                          \
            }                                                              \
        }                                                                  \
        _Pragma("unroll")                                                  \
        for (int sh = 0; sh < 2; ++sh)                                     \
            _Pragma("unroll")                                              \
            for (int ho = 0; ho < 4; ++ho)                                 \
                Vbuf[(t) * VSTR + (2 * sh + sw) * 128 + ho * 32 + wo] =    \
                    vacc[sh * 4 + ho];                                     \
    } while (0)

    // ---- wave-private pipeline: no block barriers ----
    {
        float P[NSLOT], Q[NSLOT];
        LOADS(P, t0 + 0);
        WRITEA(P); LOADS(Q, t0 + 1); COMPUTE(t0 + 0);
        WRITEA(Q); LOADS(P, t0 + 2); COMPUTE(t0 + 1);
        WRITEA(P); LOADS(Q, t0 + 3); COMPUTE(t0 + 2);
        WRITEA(Q);                   COMPUTE(t0 + 3);
    }

    __syncthreads();

    // ---- T transform (registers) + store ----
    float v[TT];
#pragma unroll
    for (int t = 0; t < TT; ++t) v[t] = Vbuf[t * VSTR + tid];

    const int subhw = tid >> 7;
    const int hoq   = (tid >> 5) & 3;
    const int wo2   = tid & 31;

    const size_t hw = (size_t)(ho0 + hoq) * WOH + (wo0 + wo2);
    const size_t ch_lo = (size_t)(subhw * CC + c);
    const size_t ch_hi = (size_t)((4 + subhw) * CC + c);
    const size_t o_lo = (((size_t)b * 24 + ch_lo) * TOH) * (HOH * WOH) + hw;
    const size_t o_hi = (((size_t)b * 24 + ch_hi) * TOH) * (HOH * WOH) + hw;

#pragma unroll
    for (int to = 0; to < TOH; ++to) {
        float lo = 0.f, hi = 0.f;
#pragma unroll
        for (int j = 0; j < 8; ++j) {
            int p = 2 * to + j - 3;
            p = p < 0 ? -p : p;
            p = p >= TT ? 2 * TT - 2 - p : p;   // folds to constant
            lo = fmaf(v[p], GLO[j], lo);
            hi = fmaf(v[p], GHI[j], hi);
        }
        out[o_lo + (size_t)to * (HOH * WOH)] = lo;
        out[o_hi + (size_t)to * (HOH * WOH)] = hi;
    }
}

extern "C" void kernel_launch(void* const* d_in, const int* in_sizes, int n_in,
                              void* d_out, int out_size, void* d_ws, size_t ws_size,
                              hipStream_t stream) {
    (void)in_sizes; (void)n_in; (void)d_ws; (void)ws_size; (void)out_size;
    const float* x = (const float*)d_in[0];
    float* out = (float*)d_out;
    dim3 grid(WOH / TW, HOH / TH, 4 * CC);   // (4, 32, 12) = 1536 blocks
    dim3 block(NTHREADS);
    hipLaunchKernelGGL(dwt3d_db4_kernel, grid, block, 0, stream, x, out);
}

// Round 6
// 67.769 us; speedup vs baseline: 2.5936x; 1.1122x over previous
//
#include <hip/hip_runtime.h>
#include <hip/hip_bf16.h>

// 3D db4 DWT, fused single kernel, wave-private slice pipeline.
// Round-6 change: Vbuf stored as bf16 (64KB -> 32KB) so total LDS ~64KB
// -> 2 blocks/CU -> inter-block phase overlap + 16 waves/CU latency hiding.
// x: [4,3,32,256,256] f32 -> out: [4,24,16,128,128] f32
// out[b, (4*st+2*sh+sw)*3+c, to, ho, wo]

#define CC 3
#define TT 32
#define HH 256
#define WW 256
#define TOH 16
#define HOH 128
#define WOH 128

#define TH 4            // output rows (h) per tile
#define TW 32           // output cols (w) per tile
#define IH 14           // 2*TH+6 input rows per slice
#define IW 70           // 2*TW+6 input cols per slice
#define ASTR 72         // LDS row stride (floats)
#define AWAVE (IH*ASTR) // 1008 floats per wave region
#define NELEM (IH*IW)   // 980 staged elements per slice
#define NSLOT 16        // ceil(980/64)
#define NW 8
#define NTHREADS 512
#define VSTR 512        // Vbuf row stride (bf16 elements)

// Pre-flipped db4 filters: g[j] = filt[7-j], so y[n] = sum_j xa[2n+j-3]*g[j]
constexpr float GLO[8] = {
     0.23037781330885523f,  0.7148465705525415f,   0.6308807679295904f,
    -0.02798376941698385f, -0.18703481171888114f,  0.030841381835986965f,
     0.032883011666982945f, -0.010597401784997278f };
constexpr float GHI[8] = {
    -0.010597401784997278f, -0.032883011666982945f, 0.030841381835986965f,
     0.18703481171888114f,  -0.02798376941698385f,  -0.6308807679295904f,
     0.7148465705525415f,   -0.23037781330885523f };

__device__ __forceinline__ int refl(int p, int n) {
    p = p < 0 ? -p : p;
    p = p >= n ? 2 * n - 2 - p : p;
    return p;
}

__global__ __launch_bounds__(NTHREADS)
void dwt3d_db4_kernel(const float* __restrict__ x, float* __restrict__ out) {
    __shared__ float Abuf[NW * AWAVE];          // 32.25 KB: per-wave input regions
    __shared__ __hip_bfloat16 Vbuf[TT * VSTR];  // 32 KB: HW-transformed, [t][col]

    const int tid  = threadIdx.x;
    const int wid  = tid >> 6;
    const int lane = tid & 63;
    const int wo   = lane & 31;          // lane's output-w column
    const int sw   = lane >> 5;          // lane's W-subband (0=lo, 1=hi)

    const int bz = blockIdx.z;           // b*CC + c
    const int b = bz / CC, c = bz - b * CC;
    const int ho0 = blockIdx.y * TH;
    const int wo0 = blockIdx.x * TW;
    const float* xs = x + (size_t)bz * (TT * HH * WW);

    // ---- staging offsets (t-invariant) ----
    int g_off[NSLOT], a_off[NSLOT];
#pragma unroll
    for (int k = 0; k < NSLOT; ++k) {
        int i = lane + 64 * k;
        int ii = i < NELEM ? i : 0;
        int r = ii / IW, cl = ii - r * IW;
        a_off[k] = wid * AWAVE + r * ASTR + cl;
        g_off[k] = refl(2 * ho0 - 3 + r, HH) * WW + refl(2 * wo0 - 3 + cl, WW);
    }

    // per-lane W weights (select by sw)
    float wG[8];
#pragma unroll
    for (int j = 0; j < 8; ++j) wG[j] = sw ? GHI[j] : GLO[j];

    const int abase = wid * AWAVE + 2 * wo;
    const int t0 = wid * 4;              // this wave's 4 slices

#define LOADS(P, t) do {                                                   \
        const float* xt = xs + (size_t)(t) * (HH * WW);                    \
        _Pragma("unroll")                                                  \
        for (int k = 0; k < NSLOT; ++k) P[k] = xt[g_off[k]];               \
    } while (0)

#define WRITEA(P) do {                                                     \
        _Pragma("unroll")                                                  \
        for (int k = 0; k < NSLOT; ++k)                                    \
            if (lane + 64 * k < NELEM) Abuf[a_off[k]] = P[k];              \
    } while (0)

    // W in LDS->reg, H entirely in registers (lane owns its (sw,wo) column)
#define COMPUTE(t) do {                                                    \
        float vacc[8] = {0.f,0.f,0.f,0.f,0.f,0.f,0.f,0.f};                 \
        _Pragma("unroll")                                                  \
        for (int r = 0; r < IH; ++r) {                                     \
            float m = 0.f;                                                 \
            _Pragma("unroll")                                              \
            for (int j = 0; j < 8; ++j)                                    \
                m = fmaf(Abuf[abase + r * ASTR + j], wG[j], m);            \
            _Pragma("unroll")                                              \
            for (int ho = 0; ho < 4; ++ho) {                               \
                const int j = r - 2 * ho;                                  \
                if (j >= 0 && j < 8) {                                     \
                    vacc[ho]     = fmaf(m, GLO[j], vacc[ho]);              \
                    vacc[4 + ho] = fmaf(m, GHI[j], vacc[4 + ho]);          \
                }                                                          \
            }                                                              \
        }                                                                  \
        _Pragma("unroll")                                                  \
        for (int sh = 0; sh < 2; ++sh)                                     \
            _Pragma("unroll")                                              \
            for (int ho = 0; ho < 4; ++ho)                                 \
                Vbuf[(t) * VSTR + (2 * sh + sw) * 128 + ho * 32 + wo] =    \
                    __float2bfloat16(vacc[sh * 4 + ho]);                   \
    } while (0)

    // ---- wave-private pipeline: no block barriers ----
    {
        float P[NSLOT], Q[NSLOT];
        LOADS(P, t0 + 0);
        WRITEA(P); LOADS(Q, t0 + 1); COMPUTE(t0 + 0);
        WRITEA(Q); LOADS(P, t0 + 2); COMPUTE(t0 + 1);
        WRITEA(P); LOADS(Q, t0 + 3); COMPUTE(t0 + 2);
        WRITEA(Q);                   COMPUTE(t0 + 3);
    }

    __syncthreads();

    // ---- T transform (registers) + store ----
    float v[TT];
#pragma unroll
    for (int t = 0; t < TT; ++t) v[t] = __bfloat162float(Vbuf[t * VSTR + tid]);

    const int subhw = tid >> 7;
    const int hoq   = (tid >> 5) & 3;
    const int wo2   = tid & 31;

    const size_t hw = (size_t)(ho0 + hoq) * WOH + (wo0 + wo2);
    const size_t ch_lo = (size_t)(subhw * CC + c);
    const size_t ch_hi = (size_t)((4 + subhw) * CC + c);
    const size_t o_lo = (((size_t)b * 24 + ch_lo) * TOH) * (HOH * WOH) + hw;
    const size_t o_hi = (((size_t)b * 24 + ch_hi) * TOH) * (HOH * WOH) + hw;

#pragma unroll
    for (int to = 0; to < TOH; ++to) {
        float lo = 0.f, hi = 0.f;
#pragma unroll
        for (int j = 0; j < 8; ++j) {
            int p = 2 * to + j - 3;
            p = p < 0 ? -p : p;
            p = p >= TT ? 2 * TT - 2 - p : p;   // folds to constant
            lo = fmaf(v[p], GLO[j], lo);
            hi = fmaf(v[p], GHI[j], hi);
        }
        out[o_lo + (size_t)to * (HOH * WOH)] = lo;
        out[o_hi + (size_t)to * (HOH * WOH)] = hi;
    }
}

extern "C" void kernel_launch(void* const* d_in, const int* in_sizes, int n_in,
                              void* d_out, int out_size, void* d_ws, size_t ws_size,
                              hipStream_t stream) {
    (void)in_sizes; (void)n_in; (void)d_ws; (void)ws_size; (void)out_size;
    const float* x = (const float*)d_in[0];
    float* out = (float*)d_out;
    dim3 grid(WOH / TW, HOH / TH, 4 * CC);   // (4, 32, 12) = 1536 blocks
    dim3 block(NTHREADS);
    hipLaunchKernelGGL(dwt3d_db4_kernel, grid, block, 0, stream, x, out);
}

// Round 8
// 46.873 us; speedup vs baseline: 3.7497x; 1.4458x over previous
//
#include <hip/hip_runtime.h>
#include <hip/hip_bf16.h>

// 3D db4 DWT, fused single kernel.
// Round-8: row-streamed staging via global_load_lds into per-wave 8-slot LDS
// ring (6 rows in flight, counted-vmcnt gated, TAIL-AWARE waits — round-7's
// bug was a constant vmcnt(10) after issue stops); XCD-aware block swizzle.
// x: [4,3,32,256,256] f32 -> out: [4,24,16,128,128] f32
// out[b, (4*st+2*sh+sw)*3+c, to, ho, wo]

#define CC 3
#define TT 32
#define HH 256
#define WW 256
#define TOH 16
#define HOH 128
#define WOH 128

#define TH 4            // output rows (h) per tile
#define TW 32           // output cols (w) per tile
#define NROWS 14        // input rows per slice (2*TH+6)
#define ROWW 70         // input cols per row (2*TW+6)
#define RSLOT 128       // ring slot stride (floats); 70 data + pad
#define NSLOTS 8        // ring slots per wave (power of 2)
#define DEPTH 6         // rows in flight per wave
#define NW 8
#define NTHREADS 512
#define VSTR 512        // Vbuf row stride (bf16 elements)
#define NRR (4*NROWS)   // 56 rows per wave

// Pre-flipped db4 filters: g[j] = filt[7-j], so y[n] = sum_j xa[2n+j-3]*g[j]
constexpr float GLO[8] = {
     0.23037781330885523f,  0.7148465705525415f,   0.6308807679295904f,
    -0.02798376941698385f, -0.18703481171888114f,  0.030841381835986965f,
     0.032883011666982945f, -0.010597401784997278f };
constexpr float GHI[8] = {
    -0.010597401784997278f, -0.032883011666982945f, 0.030841381835986965f,
     0.18703481171888114f,  -0.02798376941698385f,  -0.6308807679295904f,
     0.7148465705525415f,   -0.23037781330885523f };

__device__ __forceinline__ int refl(int p, int n) {
    p = p < 0 ? -p : p;
    p = p >= n ? 2 * n - 2 - p : p;
    return p;
}

__global__ __launch_bounds__(NTHREADS)
void dwt3d_db4_kernel(const float* __restrict__ x, float* __restrict__ out) {
    __shared__ float Ring[NW * NSLOTS * RSLOT];   // 32 KB: per-wave row rings
    __shared__ __hip_bfloat16 Vbuf[TT * VSTR];    // 32 KB: HW-transformed

    const int tid  = threadIdx.x;
    const int wid  = tid >> 6;
    const int lane = tid & 63;
    const int wo   = lane & 31;          // lane's output-w column
    const int sw   = lane >> 5;          // lane's W-subband (0=lo, 1=hi)

    // XCD-aware bijective swizzle: 1536 blocks, 8 XCDs, 192 per XCD chunk.
    // Within a chunk, consecutive ids are w/h neighbors -> halo L2 reuse.
    const int lin = blockIdx.x;
    const int nid = (lin & 7) * 192 + (lin >> 3);
    const int wo0 = (nid & 3) * TW;
    const int ho0 = ((nid >> 2) & 31) * TH;
    const int bz  = nid >> 7;            // b*CC + c
    const int b = bz / CC, c = bz - b * CC;

    const float* xs = x + (size_t)bz * (TT * HH * WW);

    // t-invariant per-lane global column offsets (reflect at w edges).
    // Chunk 1 covers cols 64..69; lanes >=6 duplicate lane 5's address
    // (same cacheline -> no extra HBM) and land in slot padding.
    const int gcol0 = refl(2 * wo0 - 3 + lane, WW);
    const int l6    = lane < 6 ? lane : 5;
    const int gcol1 = refl(2 * wo0 - 3 + 64 + l6, WW);

    // per-lane W weights (select by sw)
    float wG[8];
#pragma unroll
    for (int j = 0; j < 8; ++j) wG[j] = sw ? GHI[j] : GLO[j];

    const int t0 = wid * 4;                       // this wave's 4 slices
    const int ringbase = wid * (NSLOTS * RSLOT);

#define ISSUE(rr_) do {                                                       \
        const int t_ = (rr_) / NROWS, r_ = (rr_) % NROWS;                     \
        const int gr_ = refl(2 * ho0 - 3 + r_, HH);                           \
        const float* rowp_ = xs + (size_t)(t0 + t_) * (HH * WW) + gr_ * WW;   \
        float* lp_ = &Ring[ringbase + ((rr_) & (NSLOTS - 1)) * RSLOT];        \
        __builtin_amdgcn_global_load_lds(                                     \
            (const __attribute__((address_space(1))) void*)(rowp_ + gcol0),   \
            (__attribute__((address_space(3))) void*)lp_, 4, 0, 0);           \
        __builtin_amdgcn_global_load_lds(                                     \
            (const __attribute__((address_space(1))) void*)(rowp_ + gcol1),   \
            (__attribute__((address_space(3))) void*)(lp_ + 64), 4, 0, 0);    \
    } while (0)

    float vacc[8] = {0.f, 0.f, 0.f, 0.f, 0.f, 0.f, 0.f, 0.f};

    // prologue: DEPTH rows in flight
#pragma unroll
    for (int rr = 0; rr < DEPTH; ++rr) ISSUE(rr);

#pragma unroll
    for (int rr = 0; rr < NRR; ++rr) {
        // Gate on row rr's 2 loads. Steady state (issues still flowing):
        // outstanding before wait = 12 -> vmcnt(10) retires exactly row rr.
        // Tail (no more issues after rr=49): bound tightens by 2 per iter.
        {
            const int vm = (NRR - 1 - rr) * 2 < 10 ? (NRR - 1 - rr) * 2 : 10;
            if      (vm >= 10) asm volatile("s_waitcnt vmcnt(10)" ::: "memory");
            else if (vm == 8)  asm volatile("s_waitcnt vmcnt(8)"  ::: "memory");
            else if (vm == 6)  asm volatile("s_waitcnt vmcnt(6)"  ::: "memory");
            else if (vm == 4)  asm volatile("s_waitcnt vmcnt(4)"  ::: "memory");
            else if (vm == 2)  asm volatile("s_waitcnt vmcnt(2)"  ::: "memory");
            else               asm volatile("s_waitcnt vmcnt(0)"  ::: "memory");
        }

        // W transform of this row (taps at even base -> b64-pairable)
        const int rbase = ringbase + (rr & (NSLOTS - 1)) * RSLOT + 2 * wo;
        float m = 0.f;
#pragma unroll
        for (int j = 0; j < 8; ++j) m = fmaf(Ring[rbase + j], wG[j], m);

        // refill the ring (slot (rr+6)&7 != slots being read now or next)
        if (rr + DEPTH < NRR) ISSUE(rr + DEPTH);

        // H accumulation (indices compile-time under full unroll)
        const int r = rr % NROWS;
#pragma unroll
        for (int ho = 0; ho < 4; ++ho) {
            const int j = r - 2 * ho;
            if (j >= 0 && j < 8) {
                vacc[ho]     = fmaf(m, GLO[j], vacc[ho]);
                vacc[4 + ho] = fmaf(m, GHI[j], vacc[4 + ho]);
            }
        }

        // slice boundary: flush 8 subband values to Vbuf, reset accumulators
        if (r == NROWS - 1) {
            const int t = t0 + rr / NROWS;
#pragma unroll
            for (int sh = 0; sh < 2; ++sh)
#pragma unroll
                for (int ho = 0; ho < 4; ++ho)
                    Vbuf[t * VSTR + (2 * sh + sw) * 128 + ho * 32 + wo] =
                        __float2bfloat16(vacc[sh * 4 + ho]);
#pragma unroll
            for (int q = 0; q < 8; ++q) vacc[q] = 0.f;
        }
    }

    __syncthreads();

    // ---- T transform (registers) + store ----
    float v[TT];
#pragma unroll
    for (int t = 0; t < TT; ++t) v[t] = __bfloat162float(Vbuf[t * VSTR + tid]);

    const int subhw = tid >> 7;
    const int hoq   = (tid >> 5) & 3;
    const int wo2   = tid & 31;

    const size_t hw = (size_t)(ho0 + hoq) * WOH + (wo0 + wo2);
    const size_t ch_lo = (size_t)(subhw * CC + c);
    const size_t ch_hi = (size_t)((4 + subhw) * CC + c);
    const size_t o_lo = (((size_t)b * 24 + ch_lo) * TOH) * (HOH * WOH) + hw;
    const size_t o_hi = (((size_t)b * 24 + ch_hi) * TOH) * (HOH * WOH) + hw;

#pragma unroll
    for (int to = 0; to < TOH; ++to) {
        float lo = 0.f, hi = 0.f;
#pragma unroll
        for (int j = 0; j < 8; ++j) {
            int p = 2 * to + j - 3;
            p = p < 0 ? -p : p;
            p = p >= TT ? 2 * TT - 2 - p : p;   // folds to constant
            lo = fmaf(v[p], GLO[j], lo);
            hi = fmaf(v[p], GHI[j], hi);
        }
        out[o_lo + (size_t)to * (HOH * WOH)] = lo;
        out[o_hi + (size_t)to * (HOH * WOH)] = hi;
    }
}

extern "C" void kernel_launch(void* const* d_in, const int* in_sizes, int n_in,
                              void* d_out, int out_size, void* d_ws, size_t ws_size,
                              hipStream_t stream) {
    (void)in_sizes; (void)n_in; (void)d_ws; (void)ws_size; (void)out_size;
    const float* x = (const float*)d_in[0];
    float* out = (float*)d_out;
    dim3 grid(1536, 1, 1);               // flattened; swizzle decodes (x,y,z)
    dim3 block(NTHREADS);
    hipLaunchKernelGGL(dwt3d_db4_kernel, grid, block, 0, stream, x, out);
}

// Round 9
// 45.998 us; speedup vs baseline: 3.8211x; 1.0190x over previous
//
#include <hip/hip_runtime.h>
#include <hip/hip_bf16.h>

// 3D db4 DWT, fused single kernel.
// Round-9: parity-dedup W-phase. Lanes = (row-parity p, wo); each lane reads
// its row's 8 taps ONCE (4 float2 LDS reads) and computes BOTH lo+hi subbands
// -> W-phase LDS reads halve (they were ~56% of the saturated LDS pipe).
// Partial H-sums merged at slice end via one shfl_xor(32) per value (8/slice).
// DMA ring + counted tail-aware vmcnt gates (2-row iters: 8/8.../8,4,0).
// x: [4,3,32,256,256] f32 -> out: [4,24,16,128,128] f32
// out[b, (4*st+2*sh+sw)*3+c, to, ho, wo]

#define CC 3
#define TT 32
#define HH 256
#define WW 256
#define TOH 16
#define HOH 128
#define WOH 128

#define TH 4            // output rows (h) per tile
#define TW 32           // output cols (w) per tile
#define NROWS 14        // input rows per slice (2*TH+6)
#define RSLOT 128       // ring slot stride (floats); 70 data + pad
#define RSLOT2 64       // ring slot stride (float2)
#define NSLOTS 8        // ring slots per wave (power of 2)
#define DEPTH 6         // rows in flight per wave
#define NW 8
#define NTHREADS 512
#define VSTR 512        // Vbuf row stride (bf16 elements)
#define NRR (4*NROWS)   // 56 rows per wave
#define NIT (NRR/2)     // 28 two-row iterations

// Pre-flipped db4 filters: g[j] = filt[7-j], so y[n] = sum_j xa[2n+j-3]*g[j]
constexpr float GLO[8] = {
     0.23037781330885523f,  0.7148465705525415f,   0.6308807679295904f,
    -0.02798376941698385f, -0.18703481171888114f,  0.030841381835986965f,
     0.032883011666982945f, -0.010597401784997278f };
constexpr float GHI[8] = {
    -0.010597401784997278f, -0.032883011666982945f, 0.030841381835986965f,
     0.18703481171888114f,  -0.02798376941698385f,  -0.6308807679295904f,
     0.7148465705525415f,   -0.23037781330885523f };

__device__ __forceinline__ int refl(int p, int n) {
    p = p < 0 ? -p : p;
    p = p >= n ? 2 * n - 2 - p : p;
    return p;
}

__global__ __launch_bounds__(NTHREADS)
void dwt3d_db4_kernel(const float* __restrict__ x, float* __restrict__ out) {
    __shared__ float Ring[NW * NSLOTS * RSLOT];   // 32 KB: per-wave row rings
    __shared__ __hip_bfloat16 Vbuf[TT * VSTR];    // 32 KB: HW-transformed

    const int tid  = threadIdx.x;
    const int wid  = tid >> 6;
    const int lane = tid & 63;
    const int wo   = lane & 31;          // lane's output-w column
    const int p    = lane >> 5;          // lane's row parity (0=even,1=odd)

    // XCD-aware bijective swizzle: 1536 blocks, 8 XCDs, 192 per XCD chunk.
    const int lin = blockIdx.x;
    const int nid = (lin & 7) * 192 + (lin >> 3);
    const int wo0 = (nid & 3) * TW;
    const int ho0 = ((nid >> 2) & 31) * TH;
    const int bz  = nid >> 7;            // b*CC + c
    const int b = bz / CC, c = bz - b * CC;

    const float* xs = x + (size_t)bz * (TT * HH * WW);

    // t-invariant per-lane global column offsets (reflect at w edges).
    // Chunk 1 covers cols 64..69; lanes >=6 duplicate lane 5's address.
    const int gcol0 = refl(2 * wo0 - 3 + lane, WW);
    const int l6    = lane < 6 ? lane : 5;
    const int gcol1 = refl(2 * wo0 - 3 + 64 + l6, WW);

    // Hoisted parity-selected H weights: row r=2k'+p contributes tap
    // j = 2*(k'-ho)+p -> weight G[2d+p], d=k'-ho in [0,3].
    float wH0[4], wH1[4];
#pragma unroll
    for (int d = 0; d < 4; ++d) {
        wH0[d] = p ? GLO[2 * d + 1] : GLO[2 * d];
        wH1[d] = p ? GHI[2 * d + 1] : GHI[2 * d];
    }

    const int t0 = wid * 4;                        // this wave's 4 slices
    const int ringbase = wid * (NSLOTS * RSLOT);
    const float2* Ring2 = (const float2*)Ring;
    // lane-const float2 base: wave region + parity slot + wo
    const int r2base = wid * (NSLOTS * RSLOT2) + p * RSLOT2 + wo;
    const int vcolbase = p * 128 + wo;             // Vbuf col base (sw = p)

#define ISSUE(rr_) do {                                                       \
        const int t_ = (rr_) / NROWS, r_ = (rr_) % NROWS;                     \
        const int gr_ = refl(2 * ho0 - 3 + r_, HH);                           \
        const float* rowp_ = xs + (size_t)(t0 + t_) * (HH * WW) + gr_ * WW;   \
        float* lp_ = &Ring[ringbase + ((rr_) & (NSLOTS - 1)) * RSLOT];        \
        __builtin_amdgcn_global_load_lds(                                     \
            (const __attribute__((address_space(1))) void*)(rowp_ + gcol0),   \
            (__attribute__((address_space(3))) void*)lp_, 4, 0, 0);           \
        __builtin_amdgcn_global_load_lds(                                     \
            (const __attribute__((address_space(1))) void*)(rowp_ + gcol1),   \
            (__attribute__((address_space(3))) void*)(lp_ + 64), 4, 0, 0);    \
    } while (0)

    // H partial accumulators: vacc0 fed by m_lo (sw=0), vacc1 by m_hi (sw=1);
    // each lane accumulates only its parity's rows.
    float vacc0[2][4], vacc1[2][4];
#pragma unroll
    for (int sh = 0; sh < 2; ++sh)
#pragma unroll
        for (int ho = 0; ho < 4; ++ho) { vacc0[sh][ho] = 0.f; vacc1[sh][ho] = 0.f; }

    // prologue: DEPTH rows in flight
#pragma unroll
    for (int rr = 0; rr < DEPTH; ++rr) ISSUE(rr);

#pragma unroll
    for (int k = 0; k < NIT; ++k) {
        // Gate on rows 2k,2k+1 (2 loads each). Steady: issued=12+4k,
        // retired-needed=4k+4 -> vmcnt(8). Tail: k=26 -> 4, k=27 -> 0.
        if (k <= 25)      asm volatile("s_waitcnt vmcnt(8)" ::: "memory");
        else if (k == 26) asm volatile("s_waitcnt vmcnt(4)" ::: "memory");
        else              asm volatile("s_waitcnt vmcnt(0)" ::: "memory");

        // read this lane's row (global row 2k+p), 8 taps as 4 float2
        const int soff = ((2 * k) & (NSLOTS - 1)) * RSLOT2;  // compile-time
        const float2 d0 = Ring2[r2base + soff + 0];
        const float2 d1 = Ring2[r2base + soff + 1];
        const float2 d2 = Ring2[r2base + soff + 2];
        const float2 d3 = Ring2[r2base + soff + 3];

        // W transform: both subbands from one tap set
        float m_lo, m_hi;
        {
            float a0 = d0.x, a1 = d0.y, a2 = d1.x, a3 = d1.y;
            float a4 = d2.x, a5 = d2.y, a6 = d3.x, a7 = d3.y;
            m_lo = a0 * GLO[0]; m_hi = a0 * GHI[0];
            m_lo = fmaf(a1, GLO[1], m_lo); m_hi = fmaf(a1, GHI[1], m_hi);
            m_lo = fmaf(a2, GLO[2], m_lo); m_hi = fmaf(a2, GHI[2], m_hi);
            m_lo = fmaf(a3, GLO[3], m_lo); m_hi = fmaf(a3, GHI[3], m_hi);
            m_lo = fmaf(a4, GLO[4], m_lo); m_hi = fmaf(a4, GHI[4], m_hi);
            m_lo = fmaf(a5, GLO[5], m_lo); m_hi = fmaf(a5, GHI[5], m_hi);
            m_lo = fmaf(a6, GLO[6], m_lo); m_hi = fmaf(a6, GHI[6], m_hi);
            m_lo = fmaf(a7, GLO[7], m_lo); m_hi = fmaf(a7, GHI[7], m_hi);
        }

        // refill the ring
        if (2 * k + 6 < NRR) { ISSUE(2 * k + 6); ISSUE(2 * k + 7); }

        // H accumulation (parity-local), kk = slice-local row-pair index
        const int kk = k % 7;
#pragma unroll
        for (int ho = 0; ho < 4; ++ho) {
            const int d = kk - ho;
            if (d >= 0 && d < 4) {
                vacc0[0][ho] = fmaf(m_lo, wH0[d], vacc0[0][ho]);
                vacc0[1][ho] = fmaf(m_lo, wH1[d], vacc0[1][ho]);
                vacc1[0][ho] = fmaf(m_hi, wH0[d], vacc1[0][ho]);
                vacc1[1][ho] = fmaf(m_hi, wH1[d], vacc1[1][ho]);
            }
        }

        // slice boundary: merge parity partials across lane pairs, write Vbuf
        if (kk == 6) {
            const int t = t0 + k / 7;
#pragma unroll
            for (int sh = 0; sh < 2; ++sh)
#pragma unroll
                for (int ho = 0; ho < 4; ++ho) {
                    // send the half my partner outputs; keep the half I output
                    const float send = p ? vacc0[sh][ho] : vacc1[sh][ho];
                    const float keep = p ? vacc1[sh][ho] : vacc0[sh][ho];
                    const float recv = __shfl_xor(send, 32, 64);
                    Vbuf[t * VSTR + sh * 256 + vcolbase + ho * 32] =
                        __float2bfloat16(keep + recv);
                    vacc0[sh][ho] = 0.f; vacc1[sh][ho] = 0.f;
                }
        }
    }

    __syncthreads();

    // ---- T transform (registers) + store ----
    float v[TT];
#pragma unroll
    for (int t = 0; t < TT; ++t) v[t] = __bfloat162float(Vbuf[t * VSTR + tid]);

    const int subhw = tid >> 7;
    const int hoq   = (tid >> 5) & 3;
    const int wo2   = tid & 31;

    const size_t hw = (size_t)(ho0 + hoq) * WOH + (wo0 + wo2);
    const size_t ch_lo = (size_t)(subhw * CC + c);
    const size_t ch_hi = (size_t)((4 + subhw) * CC + c);
    const size_t o_lo = (((size_t)b * 24 + ch_lo) * TOH) * (HOH * WOH) + hw;
    const size_t o_hi = (((size_t)b * 24 + ch_hi) * TOH) * (HOH * WOH) + hw;

#pragma unroll
    for (int to = 0; to < TOH; ++to) {
        float lo = 0.f, hi = 0.f;
#pragma unroll
        for (int j = 0; j < 8; ++j) {
            int q = 2 * to + j - 3;
            q = q < 0 ? -q : q;
            q = q >= TT ? 2 * TT - 2 - q : q;   // folds to constant
            lo = fmaf(v[q], GLO[j], lo);
            hi = fmaf(v[q], GHI[j], hi);
        }
        out[o_lo + (size_t)to * (HOH * WOH)] = lo;
        out[o_hi + (size_t)to * (HOH * WOH)] = hi;
    }
}

extern "C" void kernel_launch(void* const* d_in, const int* in_sizes, int n_in,
                              void* d_out, int out_size, void* d_ws, size_t ws_size,
                              hipStream_t stream) {
    (void)in_sizes; (void)n_in; (void)d_ws; (void)ws_size; (void)out_size;
    const float* x = (const float*)d_in[0];
    float* out = (float*)d_out;
    dim3 grid(1536, 1, 1);               // flattened; swizzle decodes (x,y,z)
    dim3 block(NTHREADS);
    hipLaunchKernelGGL(dwt3d_db4_kernel, grid, block, 0, stream, x, out);
}

// Round 11
// 43.874 us; speedup vs baseline: 4.0061x; 1.0484x over previous
//
#include <hip/hip_runtime.h>
#include <hip/hip_bf16.h>

// 3D db4 DWT, fused single kernel.
// Round-11: RSLOT=72 with SAFE staging — chunk-0 covers cols -3..60 (floats
// 0..63), chunk-1 covers cols 3..66 at LDS dest lp_+6 (floats 6..69). The
// overlap (floats 6..63) is written with IDENTICAL values by both chunks, so
// the DMA write race is benign; no spill past float 69 < RSLOT. (Round-10's
// spill-into-next-slot relied on cross-DMA write ordering, which HW does not
// guarantee.) LDS 50 KB -> 3 blocks/CU, 24 waves/CU.
// x: [4,3,32,256,256] f32 -> out: [4,24,16,128,128] f32
// out[b, (4*st+2*sh+sw)*3+c, to, ho, wo]

#define CC 3
#define TT 32
#define HH 256
#define WW 256
#define TOH 16
#define HOH 128
#define WOH 128

#define TH 4            // output rows (h) per tile
#define TW 32           // output cols (w) per tile
#define NROWS 14        // input rows per slice (2*TH+6)
#define RSLOT 72        // ring slot stride (floats); 70 data + 2 pad
#define RSLOT2 36       // ring slot stride (float2)
#define NSLOTS 8        // ring slots per wave (power of 2)
#define DEPTH 6         // rows in flight per wave
#define NW 8
#define NTHREADS 512
#define VSTR 512        // Vbuf row stride (bf16 elements)
#define NRR (4*NROWS)   // 56 rows per wave
#define NIT (NRR/2)     // 28 two-row iterations

// Pre-flipped db4 filters: g[j] = filt[7-j], so y[n] = sum_j xa[2n+j-3]*g[j]
constexpr float GLO[8] = {
     0.23037781330885523f,  0.7148465705525415f,   0.6308807679295904f,
    -0.02798376941698385f, -0.18703481171888114f,  0.030841381835986965f,
     0.032883011666982945f, -0.010597401784997278f };
constexpr float GHI[8] = {
    -0.010597401784997278f, -0.032883011666982945f, 0.030841381835986965f,
     0.18703481171888114f,  -0.02798376941698385f,  -0.6308807679295904f,
     0.7148465705525415f,   -0.23037781330885523f };

__device__ __forceinline__ int refl(int p, int n) {
    p = p < 0 ? -p : p;
    p = p >= n ? 2 * n - 2 - p : p;
    return p;
}

__global__ __launch_bounds__(NTHREADS)
void dwt3d_db4_kernel(const float* __restrict__ x, float* __restrict__ out) {
    __shared__ float Ring[NW * NSLOTS * RSLOT];   // 18 KB: per-wave row rings
    __shared__ __hip_bfloat16 Vbuf[TT * VSTR];    // 32 KB: HW-transformed

    const int tid  = threadIdx.x;
    const int wid  = tid >> 6;
    const int lane = tid & 63;
    const int wo   = lane & 31;          // lane's output-w column
    const int p    = lane >> 5;          // lane's row parity (0=even,1=odd)

    // XCD-aware bijective swizzle: 1536 blocks, 8 XCDs, 192 per XCD chunk.
    const int lin = blockIdx.x;
    const int nid = (lin & 7) * 192 + (lin >> 3);
    const int wo0 = (nid & 3) * TW;
    const int ho0 = ((nid >> 2) & 31) * TH;
    const int bz  = nid >> 7;            // b*CC + c
    const int b = bz / CC, c = bz - b * CC;

    const float* xs = x + (size_t)bz * (TT * HH * WW);

    // t-invariant per-lane global column offsets (reflect at w edges).
    // chunk-0: cols -3..60 -> slot floats 0..63 (dest lp_)
    // chunk-1: cols  3..66 -> slot floats 6..69 (dest lp_+6)
    // Overlap floats 6..63 get identical values from both chunks (col(f) =
    // 2*wo0-3+f for each) -> benign write race, zero spill past float 69.
    const int gcol0 = refl(2 * wo0 - 3 + lane, WW);
    const int gcol1 = refl(2 * wo0 + 3 + lane, WW);

    // Hoisted parity-selected H weights: row r=2k'+p contributes tap
    // j = 2*(k'-ho)+p -> weight G[2d+p], d=k'-ho in [0,3].
    float wH0[4], wH1[4];
#pragma unroll
    for (int d = 0; d < 4; ++d) {
        wH0[d] = p ? GLO[2 * d + 1] : GLO[2 * d];
        wH1[d] = p ? GHI[2 * d + 1] : GHI[2 * d];
    }

    const int t0 = wid * 4;                        // this wave's 4 slices
    const int ringbase = wid * (NSLOTS * RSLOT);
    const float2* Ring2 = (const float2*)Ring;
    // lane-const float2 base: wave region + parity slot + wo
    const int r2base = wid * (NSLOTS * RSLOT2) + p * RSLOT2 + wo;
    const int vcolbase = p * 128 + wo;             // Vbuf col base (sw = p)

#define ISSUE(rr_) do {                                                       \
        const int t_ = (rr_) / NROWS, r_ = (rr_) % NROWS;                     \
        const int gr_ = refl(2 * ho0 - 3 + r_, HH);                           \
        const float* rowp_ = xs + (size_t)(t0 + t_) * (HH * WW) + gr_ * WW;   \
        float* lp_ = &Ring[ringbase + ((rr_) & (NSLOTS - 1)) * RSLOT];        \
        __builtin_amdgcn_global_load_lds(                                     \
            (const __attribute__((address_space(1))) void*)(rowp_ + gcol0),   \
            (__attribute__((address_space(3))) void*)lp_, 4, 0, 0);           \
        __builtin_amdgcn_global_load_lds(                                     \
            (const __attribute__((address_space(1))) void*)(rowp_ + gcol1),   \
            (__attribute__((address_space(3))) void*)(lp_ + 6), 4, 0, 0);     \
    } while (0)

    // H partial accumulators: vacc0 fed by m_lo (sw=0), vacc1 by m_hi (sw=1);
    // each lane accumulates only its parity's rows.
    float vacc0[2][4], vacc1[2][4];
#pragma unroll
    for (int sh = 0; sh < 2; ++sh)
#pragma unroll
        for (int ho = 0; ho < 4; ++ho) { vacc0[sh][ho] = 0.f; vacc1[sh][ho] = 0.f; }

    // prologue: DEPTH rows in flight
#pragma unroll
    for (int rr = 0; rr < DEPTH; ++rr) ISSUE(rr);

#pragma unroll
    for (int k = 0; k < NIT; ++k) {
        // Gate on rows 2k,2k+1 (2 loads each). Steady: issued=12+4k,
        // retired-needed=4k+4 -> vmcnt(8). Tail: k=26 -> 4, k=27 -> 0.
        if (k <= 25)      asm volatile("s_waitcnt vmcnt(8)" ::: "memory");
        else if (k == 26) asm volatile("s_waitcnt vmcnt(4)" ::: "memory");
        else              asm volatile("s_waitcnt vmcnt(0)" ::: "memory");

        // read this lane's row (global row 2k+p), 8 taps as 4 float2
        const int soff = ((2 * k) & (NSLOTS - 1)) * RSLOT2;  // compile-time
        const float2 d0 = Ring2[r2base + soff + 0];
        const float2 d1 = Ring2[r2base + soff + 1];
        const float2 d2 = Ring2[r2base + soff + 2];
        const float2 d3 = Ring2[r2base + soff + 3];

        // W transform: both subbands from one tap set
        float m_lo, m_hi;
        {
            float a0 = d0.x, a1 = d0.y, a2 = d1.x, a3 = d1.y;
            float a4 = d2.x, a5 = d2.y, a6 = d3.x, a7 = d3.y;
            m_lo = a0 * GLO[0]; m_hi = a0 * GHI[0];
            m_lo = fmaf(a1, GLO[1], m_lo); m_hi = fmaf(a1, GHI[1], m_hi);
            m_lo = fmaf(a2, GLO[2], m_lo); m_hi = fmaf(a2, GHI[2], m_hi);
            m_lo = fmaf(a3, GLO[3], m_lo); m_hi = fmaf(a3, GHI[3], m_hi);
            m_lo = fmaf(a4, GLO[4], m_lo); m_hi = fmaf(a4, GHI[4], m_hi);
            m_lo = fmaf(a5, GLO[5], m_lo); m_hi = fmaf(a5, GHI[5], m_hi);
            m_lo = fmaf(a6, GLO[6], m_lo); m_hi = fmaf(a6, GHI[6], m_hi);
            m_lo = fmaf(a7, GLO[7], m_lo); m_hi = fmaf(a7, GHI[7], m_hi);
        }

        // refill the ring (writes slots read 2 iterations ago)
        if (2 * k + 6 < NRR) { ISSUE(2 * k + 6); ISSUE(2 * k + 7); }

        // H accumulation (parity-local), kk = slice-local row-pair index
        const int kk = k % 7;
#pragma unroll
        for (int ho = 0; ho < 4; ++ho) {
            const int d = kk - ho;
            if (d >= 0 && d < 4) {
                vacc0[0][ho] = fmaf(m_lo, wH0[d], vacc0[0][ho]);
                vacc0[1][ho] = fmaf(m_lo, wH1[d], vacc0[1][ho]);
                vacc1[0][ho] = fmaf(m_hi, wH0[d], vacc1[0][ho]);
                vacc1[1][ho] = fmaf(m_hi, wH1[d], vacc1[1][ho]);
            }
        }

        // slice boundary: merge parity partials across lane pairs, write Vbuf
        if (kk == 6) {
            const int t = t0 + k / 7;
#pragma unroll
            for (int sh = 0; sh < 2; ++sh)
#pragma unroll
                for (int ho = 0; ho < 4; ++ho) {
                    // send the half my partner outputs; keep the half I output
                    const float send = p ? vacc0[sh][ho] : vacc1[sh][ho];
                    const float keep = p ? vacc1[sh][ho] : vacc0[sh][ho];
                    const float recv = __shfl_xor(send, 32, 64);
                    Vbuf[t * VSTR + sh * 256 + vcolbase + ho * 32] =
                        __float2bfloat16(keep + recv);
                    vacc0[sh][ho] = 0.f; vacc1[sh][ho] = 0.f;
                }
        }
    }

    __syncthreads();

    // ---- T transform (registers) + store ----
    float v[TT];
#pragma unroll
    for (int t = 0; t < TT; ++t) v[t] = __bfloat162float(Vbuf[t * VSTR + tid]);

    const int subhw = tid >> 7;
    const int hoq   = (tid >> 5) & 3;
    const int wo2   = tid & 31;

    const size_t hw = (size_t)(ho0 + hoq) * WOH + (wo0 + wo2);
    const size_t ch_lo = (size_t)(subhw * CC + c);
    const size_t ch_hi = (size_t)((4 + subhw) * CC + c);
    const size_t o_lo = (((size_t)b * 24 + ch_lo) * TOH) * (HOH * WOH) + hw;
    const size_t o_hi = (((size_t)b * 24 + ch_hi) * TOH) * (HOH * WOH) + hw;

#pragma unroll
    for (int to = 0; to < TOH; ++to) {
        float lo = 0.f, hi = 0.f;
#pragma unroll
        for (int j = 0; j < 8; ++j) {
            int q = 2 * to + j - 3;
            q = q < 0 ? -q : q;
            q = q >= TT ? 2 * TT - 2 - q : q;   // folds to constant
            lo = fmaf(v[q], GLO[j], lo);
            hi = fmaf(v[q], GHI[j], hi);
        }
        out[o_lo + (size_t)to * (HOH * WOH)] = lo;
        out[o_hi + (size_t)to * (HOH * WOH)] = hi;
    }
}

extern "C" void kernel_launch(void* const* d_in, const int* in_sizes, int n_in,
                              void* d_out, int out_size, void* d_ws, size_t ws_size,
                              hipStream_t stream) {
    (void)in_sizes; (void)n_in; (void)d_ws; (void)ws_size; (void)out_size;
    const float* x = (const float*)d_in[0];
    float* out = (float*)d_out;
    dim3 grid(1536, 1, 1);               // flattened; swizzle decodes (x,y,z)
    dim3 block(NTHREADS);
    hipLaunchKernelGGL(dwt3d_db4_kernel, grid, block, 0, stream, x, out);
}